// Round 14
// baseline (6188.160 us; speedup 1.0000x reference)
//
#include <hip/hip_runtime.h>
#include <stddef.h>
#include <stdint.h>

// Problem dims (fixed by the reference)
#define BB 32
#define TT 2048
#define NI 128
#define NH 512
#define NO 128

// d_out layout (floats): z[BB*NO] | X[BB*TT*NH] | As[BB*TT*NH] | Phis[BB*TT*NH]
#define Z_OFS   0
#define X_OFS   (BB * NO)
#define AS_OFS  (X_OFS + (size_t)BB * TT * NH)
#define PHI_OFS (AS_OFS + (size_t)BB * TT * NH)

// Scan: 4 WGs per batch (128 WGs, 512 thr). Thread (rg=tid>>4, cg=tid&15)
// owns a 4-row x 32-col weight block (64 f32x2 regs). Per step: FMA ->
// in-wave butterfly reduce -> lanes cg<4 produce -> lanes tid<384 poll one
// remote u64 -> ONE barrier. x double-buffered in LDS.
//
// Exchange = DUAL RAIL, self-adapting, hang-proof:
//   rail A: sc0 store / sc0 load  -> resolves in the XCD L2 when producer
//           and consumer share an XCD (fast, ~4x lower RT than MALL)
//   rail B: relaxed agent atomics  -> resolves at MALL (proven, R12)
// Producers write BOTH rails (2 stores, fire-and-forget). Consumers poll
// rail A, but every 16th iteration read rail B -- guaranteed progress even
// if rail A is stale/mis-scoped (cross-XCD placement, cache-fill staleness).
#define WGPB 4
#define ROWS 128
#define NTHR 512

// d_ws: xtagA[2][BB][NH] u64 (sc0 rail) | xtagB[2][BB][NH] u64 (sc1 rail)
#define XTAG_U64   (2 * BB * NH)
#define XTAG_BYTES (XTAG_U64 * 8)

typedef float f32x2 __attribute__((ext_vector_type(2)));

// x swizzle within a buffer: value c lives at c + (c>>5)*4 (36-f32 groups)
#define SW(c) ((c) + (((c) >> 5) << 2))
#define XBUF 576

__device__ __forceinline__ float fast_tanh(float x) {
    float e = __builtin_exp2f(x * 2.8853900817779268f);
    return 1.0f - 2.0f * __builtin_amdgcn_rcpf(e + 1.0f);
}

// sc0 store: write-through to the XCD L2 (SE-scope; bypasses CU-local cache)
__device__ __forceinline__ void l2_store_u64(unsigned long long* p,
                                             unsigned long long v) {
    asm volatile("global_store_dwordx2 %0, %1, off sc0"
                 :: "v"(p), "v"(v) : "memory");
}

// sc0 load: bypass CU-local cache, read the XCD L2
__device__ __forceinline__ unsigned long long l2_load_u64(
        const unsigned long long* p) {
    unsigned long long r;
    asm volatile("global_load_dwordx2 %0, %1, off sc0\n\t"
                 "s_waitcnt vmcnt(0)"
                 : "=v"(r) : "v"(p) : "memory");
    return r;
}

// ---------------------------------------------------------------------------
// Kernel 1: ui[bt][h] = sum_k u[bt][k] * Wi[h][k]   (written into As region)
// ---------------------------------------------------------------------------
__global__ void __launch_bounds__(256) ui_gemm(const float* __restrict__ u,
                                               const float* __restrict__ Wi,
                                               float* __restrict__ ui_out) {
    __shared__ float Au[64][NI + 1];
    __shared__ float Bw[64][NI + 1];
    const int tid = threadIdx.x;
    const int bt0 = blockIdx.x * 64;
    const int h0  = blockIdx.y * 64;

    for (int idx = tid; idx < 64 * (NI / 4); idx += 256) {
        const int r = idx >> 5;
        const int c = (idx & 31) << 2;
        float4 va = *reinterpret_cast<const float4*>(&u[(size_t)(bt0 + r) * NI + c]);
        Au[r][c + 0] = va.x; Au[r][c + 1] = va.y; Au[r][c + 2] = va.z; Au[r][c + 3] = va.w;
        float4 vb = *reinterpret_cast<const float4*>(&Wi[(size_t)(h0 + r) * NI + c]);
        Bw[r][c + 0] = vb.x; Bw[r][c + 1] = vb.y; Bw[r][c + 2] = vb.z; Bw[r][c + 3] = vb.w;
    }
    __syncthreads();

    const int tx = tid & 15;
    const int ty = tid >> 4;
    float acc[4][4] = {};
    for (int k = 0; k < NI; ++k) {
        float a_[4], b_[4];
#pragma unroll
        for (int i = 0; i < 4; ++i) a_[i] = Au[ty * 4 + i][k];
#pragma unroll
        for (int jj = 0; jj < 4; ++jj) b_[jj] = Bw[tx * 4 + jj][k];
#pragma unroll
        for (int i = 0; i < 4; ++i)
#pragma unroll
            for (int jj = 0; jj < 4; ++jj) acc[i][jj] += a_[i] * b_[jj];
    }
#pragma unroll
    for (int i = 0; i < 4; ++i)
#pragma unroll
        for (int jj = 0; jj < 4; ++jj)
            ui_out[(size_t)(bt0 + ty * 4 + i) * NH + (h0 + tx * 4 + jj)] = acc[i][jj];
}

// ---------------------------------------------------------------------------
// Kernel 2: 4-WG-per-batch scan; dual-rail (L2-fast / MALL-guaranteed).
// ---------------------------------------------------------------------------
__global__ void __launch_bounds__(NTHR)
rnn_scan4(const float* __restrict__ Wr, float* __restrict__ out,
          unsigned long long* __restrict__ xtagA,
          unsigned long long* __restrict__ xtagB) {
    const int blk = blockIdx.x;            // j*32 + b
    const int b   = blk & (BB - 1);
    const int j   = blk >> 5;              // 0..3
    const int h0  = j * ROWS;
    const int tid = threadIdx.x;
    const int rg  = tid >> 4;              // 0..31: rows h0+4rg .. +3
    const int cg  = tid & 15;              // cols 32cg .. +32

    __shared__ float x_swz[2][XBUF];       // double-buffered swizzled state

    // ---- weights: 4 rows x 32 cols -> 64 pinned f32x2
    f32x2 w2[64];
    {
        const float* wb = Wr + (size_t)(h0 + 4 * rg) * NH + 32 * cg;
#pragma unroll
        for (int k = 0; k < 4; ++k)
#pragma unroll
            for (int i = 0; i < 8; ++i) {
                float4 t4 = *reinterpret_cast<const float4*>(&wb[(size_t)k * NH + 4 * i]);
                w2[k * 16 + 2 * i]     = (f32x2){t4.x, t4.y};
                w2[k * 16 + 2 * i + 1] = (f32x2){t4.z, t4.w};
            }
#pragma unroll
        for (int i = 0; i < 64; ++i)
            asm volatile("" : "+v"(w2[i]));
    }

    float* __restrict__ Xp  = out + X_OFS   + (size_t)b * TT * NH;
    float* __restrict__ Asp = out + AS_OFS  + (size_t)b * TT * NH;
    float* __restrict__ Php = out + PHI_OFS + (size_t)b * TT * NH;

    for (int m = tid; m < XBUF; m += NTHR) {    // x0 = 0
        x_swz[0][m] = 0.0f;
        x_swz[1][m] = 0.0f;
    }

    // producer lanes: cg<4 own row h0+4rg+cg
    const bool prod  = (cg < 4);
    const int  myrow = 4 * rg + cg;

    // poller lanes: tid<384 own one remote u64
    const bool poll  = (tid < 384);
    const int  pjj   = (j + 1 + (tid >> 7)) & 3;
    const int  pidx  = tid & 127;

    float uival = 0.0f;
    if (prod) uival = Asp[h0 + myrow];

    float da = 0.f, dph = 0.f;
    size_t dpo = 0;

    __syncthreads();

    for (int t = 0; t < TT; ++t) {
        const int cur = t & 1, nxt = cur ^ 1;

        // ---- deferred output stores (step t-1) + next-ui prefetch
        float nui = 0.0f;
        if (prod) {
            if (t > 0) {
                __builtin_nontemporal_store(da,  &Asp[dpo]);
                __builtin_nontemporal_store(dph, &Xp[dpo]);
                __builtin_nontemporal_store(dph, &Php[dpo]);
            }
            if (t + 1 < TT) nui = Asp[(size_t)(t + 1) * NH + h0 + myrow];
        }

        // ---- FMA: 4 rows x 32 cols; 8 x-float4 reads from buf[cur]
        f32x2 a0 = {0.f, 0.f}, a1 = {0.f, 0.f}, a2 = {0.f, 0.f}, a3 = {0.f, 0.f};
        const float* xg = &x_swz[cur][cg * 36];
#pragma unroll
        for (int i = 0; i < 8; ++i) {
            float4 xv = *reinterpret_cast<const float4*>(&xg[4 * i]);
            f32x2 xa = {xv.x, xv.y};
            f32x2 xb = {xv.z, xv.w};
            a0 = __builtin_elementwise_fma(w2[      2 * i],     xa, a0);
            a0 = __builtin_elementwise_fma(w2[      2 * i + 1], xb, a0);
            a1 = __builtin_elementwise_fma(w2[16  + 2 * i],     xa, a1);
            a1 = __builtin_elementwise_fma(w2[16  + 2 * i + 1], xb, a1);
            a2 = __builtin_elementwise_fma(w2[32  + 2 * i],     xa, a2);
            a2 = __builtin_elementwise_fma(w2[32  + 2 * i + 1], xb, a2);
            a3 = __builtin_elementwise_fma(w2[48  + 2 * i],     xa, a3);
            a3 = __builtin_elementwise_fma(w2[48  + 2 * i + 1], xb, a3);
        }
        float4 pv;
        pv.x = a0.x + a0.y;
        pv.y = a1.x + a1.y;
        pv.z = a2.x + a2.y;
        pv.w = a3.x + a3.y;

        // ---- in-wave butterfly over cg
#pragma unroll
        for (int mask = 1; mask <= 8; mask <<= 1) {
            pv.x += __shfl_xor(pv.x, mask);
            pv.y += __shfl_xor(pv.y, mask);
            pv.z += __shfl_xor(pv.z, mask);
            pv.w += __shfl_xor(pv.w, mask);
        }

        // ---- produce: both rails
        if (prod) {
            float s = (cg == 0) ? pv.x : (cg == 1) ? pv.y : (cg == 2) ? pv.z : pv.w;
            s += uival;
            const float phi = fast_tanh(s);
            x_swz[nxt][SW(h0 + myrow)] = phi;
            if (t + 1 < TT) {
                union { float f; unsigned u; } cv;
                cv.f = phi;
                const unsigned long long pack =
                    ((unsigned long long)(unsigned)(t + 1) << 32) | cv.u;
                const size_t off = ((size_t)(nxt) * BB + b) * NH + h0 + myrow;
                l2_store_u64(&xtagA[off], pack);           // rail A: XCD L2
                __hip_atomic_store(&xtagB[off], pack,      // rail B: MALL
                                   __ATOMIC_RELAXED, __HIP_MEMORY_SCOPE_AGENT);
            }
            da  = s;
            dph = phi;
            dpo = (size_t)t * NH + h0 + myrow;
            uival = nui;
        }

        // ---- poll one remote value: rail A fast, rail B every 16th iter
        if (poll && t + 1 < TT) {
            const unsigned want = (unsigned)(t + 1);
            const size_t off =
                ((size_t)(nxt) * BB + b) * NH + pjj * ROWS + pidx;
            const unsigned long long* pA = xtagA + off;
            const unsigned long long* pB = xtagB + off;
            unsigned long long r;
            int spin = 0;
            do {
                if ((spin++ & 15) != 15)
                    r = l2_load_u64(pA);
                else
                    r = __hip_atomic_load(pB, __ATOMIC_RELAXED,
                                          __HIP_MEMORY_SCOPE_AGENT);
            } while ((unsigned)(r >> 32) != want);
            union { unsigned u; float f; } v;
            v.u = (unsigned)r;
            x_swz[nxt][SW(pjj * ROWS + pidx)] = v.f;
        }
        __syncthreads();
    }

    // final deferred outputs (t = TT-1)
    if (prod) {
        __builtin_nontemporal_store(da,  &Asp[dpo]);
        __builtin_nontemporal_store(dph, &Xp[dpo]);
        __builtin_nontemporal_store(dph, &Php[dpo]);
    }
}

// ---------------------------------------------------------------------------
// Kernel 3: z[b][o] = sum_h X[b][T-1][h] * Wo[o][h]
// ---------------------------------------------------------------------------
__global__ void __launch_bounds__(128) z_gemv(const float* __restrict__ Wo,
                                              float* __restrict__ out) {
    const int b = blockIdx.x;
    const int o = threadIdx.x;
    __shared__ float xl[NH];
    const float* Xlast = out + X_OFS + (size_t)b * TT * NH + (size_t)(TT - 1) * NH;
    for (int h = threadIdx.x; h < NH; h += 128) xl[h] = Xlast[h];
    __syncthreads();
    float acc = 0.f;
#pragma unroll 4
    for (int h4 = 0; h4 < NH / 4; ++h4) {
        float4 w = *reinterpret_cast<const float4*>(&Wo[(size_t)o * NH + h4 * 4]);
        acc += xl[h4 * 4 + 0] * w.x + xl[h4 * 4 + 1] * w.y +
               xl[h4 * 4 + 2] * w.z + xl[h4 * 4 + 3] * w.w;
    }
    out[Z_OFS + (size_t)b * NO + o] = acc;
}

// ---------------------------------------------------------------------------
extern "C" void kernel_launch(void* const* d_in, const int* in_sizes, int n_in,
                              void* d_out, int out_size, void* d_ws, size_t ws_size,
                              hipStream_t stream) {
    const float* u  = (const float*)d_in[0];
    const float* Wr = (const float*)d_in[1];
    const float* Wi = (const float*)d_in[2];
    const float* Wo = (const float*)d_in[3];
    float* out = (float*)d_out;

    unsigned long long* xtagA = (unsigned long long*)d_ws;
    unsigned long long* xtagB = xtagA + XTAG_U64;

    // reset both tag rails each replay (stale tags would alias)
    hipMemsetAsync(d_ws, 0, 2 * XTAG_BYTES, stream);

    // ui -> As region of d_out (scan reads it there, then overwrites with a)
    ui_gemm<<<dim3((BB * TT) / 64, NH / 64), 256, 0, stream>>>(u, Wi, out + AS_OFS);

    rnn_scan4<<<BB * WGPB, NTHR, 0, stream>>>(Wr, out, xtagA, xtagB);

    z_gemv<<<BB, 128, 0, stream>>>(Wo, out);
}